// Round 1
// baseline (280.251 us; speedup 1.0000x reference)
//
#include <hip/hip_runtime.h>
#include <math.h>

// Problem constants: B=4, T=2048, C=1024, NH=16, H=64
#define T_LEN 2048
#define C_DIM 1024
#define C3    3072
#define NHEAD 16
#define HDIM  64

typedef __attribute__((ext_vector_type(8))) __bf16 bf16x8;
typedef __attribute__((ext_vector_type(8))) unsigned short u16x8;
typedef __attribute__((ext_vector_type(4))) float f32x4;
typedef unsigned short ushort_t;

#define QK_SCALE 0.180336878f   // 1/sqrt(64) * log2(e), folded into Q

#if defined(__has_builtin)
#if __has_builtin(__builtin_amdgcn_exp2f)
#define FAST_EXP2(x) __builtin_amdgcn_exp2f(x)
#endif
#endif
#ifndef FAST_EXP2
#define FAST_EXP2(x) exp2f(x)
#endif

__device__ __forceinline__ ushort_t f2bf(float f) {
    unsigned int u = __float_as_uint(f);
    unsigned int r = (u + 0x7FFFu + ((u >> 16) & 1u)) >> 16;  // RNE
    return (ushort_t)r;
}

#define GLL16(g, l) __builtin_amdgcn_global_load_lds( \
    (const __attribute__((address_space(1))) void*)(g), \
    (__attribute__((address_space(3))) void*)(l), 16, 0, 0)

// ---------------------------------------------------------------------------
// Fused prep: x cast (blocks 0..8191), W_attn transpose (8192..8959),
// W_proj transpose (8960..9215).
// ---------------------------------------------------------------------------
__global__ __launch_bounds__(256) void prep_inputs(
    const float* __restrict__ x, ushort_t* __restrict__ xb,
    const float* __restrict__ W1, ushort_t* __restrict__ Wt1,
    const float* __restrict__ W2, ushort_t* __restrict__ Wt2)
{
    __shared__ float t[64][65];
    const int bx = blockIdx.x;
    if (bx < 8192) {
        const int i = bx * 256 + threadIdx.x;
        const float4 v = ((const float4*)x)[i];
        ushort4 o;
        o.x = f2bf(v.x); o.y = f2bf(v.y); o.z = f2bf(v.z); o.w = f2bf(v.w);
        ((ushort4*)xb)[i] = o;
        return;
    }
    const float* W; ushort_t* Wt; int N, n0, k0;
    if (bx < 8960) {
        const int tt = bx - 8192;
        W = W1; Wt = Wt1; N = C3;
        n0 = (tt % 48) * 64; k0 = (tt / 48) * 64;
    } else {
        const int tt = bx - 8960;
        W = W2; Wt = Wt2; N = C_DIM;
        n0 = (tt % 16) * 64; k0 = (tt / 16) * 64;
    }
    const int K = C_DIM;
    const int c = threadIdx.x & 63, r4 = threadIdx.x >> 6;
#pragma unroll
    for (int i = 0; i < 16; i++) {
        int r = i * 4 + r4;
        t[r][c] = W[(size_t)(k0 + r) * N + n0 + c];
    }
    __syncthreads();
#pragma unroll
    for (int i = 0; i < 16; i++) {
        int r = i * 4 + r4;
        Wt[(size_t)(n0 + r) * K + k0 + c] = f2bf(t[c][r]);
    }
}

// ---------------------------------------------------------------------------
// bf16 MFMA GEMM: 128x128 tile, BK=64, 256 threads, XOR-swizzled unpadded
// LDS staged via global_load_lds width=16. Logical chunk c of row m sits at
// position c^(m&7); frag readers use pos=(4s+quad)^(r16&7) -> uniform banks.
// ---------------------------------------------------------------------------
template <bool OUT_BF16, bool QSCALE>
__global__ __launch_bounds__(256, 3) void gemm_bt_mfma(
    const ushort_t* __restrict__ A, const ushort_t* __restrict__ Bt,
    const float* __restrict__ bias, void* __restrict__ Cv,
    int M, int N, int K)
{
    __shared__ ushort_t Alds[128 * 64];   // 16 KB
    __shared__ ushort_t Blds[128 * 64];   // 16 KB

    const int tid = threadIdx.x;
    const int m0 = blockIdx.y * 128;
    const int n0 = blockIdx.x * 128;
    const int w = tid >> 6;
    const int ln = tid & 63;
    const int quad = ln >> 4;
    const int r16 = ln & 15;
    const int wr0 = (w & 1) * 64;
    const int wc0 = (w >> 1) * 64;

    f32x4 acc[4][4] = {};

    const int srow = tid >> 3;                       // 0..31 (row within round)
    const int csrc8 = ((tid & 7) ^ (srow & 7)) * 8;  // swizzled source elem ofs
    const int sw = r16 & 7;

    for (int k0 = 0; k0 < K; k0 += 64) {
#pragma unroll
        for (int rr = 0; rr < 4; rr++) {
            const ushort_t* ga = A + (size_t)(m0 + rr * 32 + srow) * K + k0 + csrc8;
            GLL16(ga, Alds + rr * 2048 + tid * 8);
            const ushort_t* gb = Bt + (size_t)(n0 + rr * 32 + srow) * K + k0 + csrc8;
            GLL16(gb, Blds + rr * 2048 + tid * 8);
        }
        __syncthreads();

#pragma unroll
        for (int s = 0; s < 2; s++) {
            const int cpos = ((4 * s + quad) ^ sw) * 8;
            bf16x8 af[4], bfr[4];
#pragma unroll
            for (int i = 0; i < 4; i++)
                af[i] = *(const bf16x8*)(Alds + (wr0 + i * 16 + r16) * 64 + cpos);
#pragma unroll
            for (int j = 0; j < 4; j++)
                bfr[j] = *(const bf16x8*)(Blds + (wc0 + j * 16 + r16) * 64 + cpos);
#pragma unroll
            for (int i = 0; i < 4; i++)
#pragma unroll
                for (int j = 0; j < 4; j++)
                    acc[i][j] = __builtin_amdgcn_mfma_f32_16x16x32_bf16(
                        af[i], bfr[j], acc[i][j], 0, 0, 0);
        }
        __syncthreads();
    }

    const float scl = (QSCALE && n0 < C_DIM) ? QK_SCALE : 1.0f;

#pragma unroll
    for (int j = 0; j < 4; j++) {
        const int col = n0 + wc0 + j * 16 + r16;
        const float bv = bias[col];
#pragma unroll
        for (int i = 0; i < 4; i++) {
            const int rowb = m0 + wr0 + i * 16 + quad * 4;
#pragma unroll
            for (int r = 0; r < 4; r++) {
                const float v = (acc[i][j][r] + bv) * scl;
                if (OUT_BF16)
                    ((ushort_t*)Cv)[(size_t)(rowb + r) * N + col] = f2bf(v);
                else
                    ((float*)Cv)[(size_t)(rowb + r) * N + col] = v;
            }
        }
    }
}

// ---------------------------------------------------------------------------
// V pre-transpose: qkv V-slice [b][t][2C + h*64 + d] -> vtg[bh][d][t]
// ---------------------------------------------------------------------------
__global__ __launch_bounds__(256) void transpose_v(
    const ushort_t* __restrict__ qkv, ushort_t* __restrict__ vtg)
{
    __shared__ ushort_t Ts[64][72];
    const int t0 = blockIdx.x * 64;
    const int bh = blockIdx.y;
    const int b = bh >> 4, h = bh & 15;
    const ushort_t* src = qkv + (size_t)b * T_LEN * C3 + 2 * C_DIM + h * HDIM;
    const int tid = threadIdx.x;
    {
        const int r = tid >> 2, cs = (tid & 3) * 16;
        *(u16x8*)(&Ts[r][cs])     = *(const u16x8*)(src + (size_t)(t0 + r) * C3 + cs);
        *(u16x8*)(&Ts[r][cs + 8]) = *(const u16x8*)(src + (size_t)(t0 + r) * C3 + cs + 8);
    }
    __syncthreads();
    {
        const int d = tid >> 2, ts0 = (tid & 3) * 16;
        ushort_t* dst = vtg + ((size_t)bh * HDIM + d) * T_LEN + t0 + ts0;
        u16x8 o0, o1;
#pragma unroll
        for (int j = 0; j < 8; j++) o0[j] = Ts[ts0 + j][d];
#pragma unroll
        for (int j = 0; j < 8; j++) o1[j] = Ts[ts0 + 8 + j][d];
        *(u16x8*)dst = o0;
        *(u16x8*)(dst + 8) = o1;
    }
}

// ---------------------------------------------------------------------------
// MFMA flash attention v6: v5 + double-buffered K/V staging.
// Stage(kt+1) is issued right after the single per-iteration barrier, so the
// vmcnt(0) drain that __syncthreads emits at the NEXT barrier lands after a
// full iteration of MFMA+softmax has covered the load latency (T3-lite,
// depth-1 pipeline via buffer parity). One barrier per kt instead of two.
// LDS: 18K QP + 16K Ks[2] + 16K Vs[2] = 50 KB -> 3 blocks/CU.
// ---------------------------------------------------------------------------
#define QPITCH 72

// exp2 -> per-lane partial sum -> P store (RTZ bf16 via v_perm).
__device__ __forceinline__ void softmax_store(
    f32x4 (&s)[4], float& lacc, ushort_t* __restrict__ QP,
    int prow, int quad)
{
#pragma unroll
    for (int mb = 0; mb < 4; mb++) {
        const float p0 = FAST_EXP2(s[mb][0]);
        const float p1 = FAST_EXP2(s[mb][1]);
        const float p2 = FAST_EXP2(s[mb][2]);
        const float p3 = FAST_EXP2(s[mb][3]);
        lacc += (p0 + p1) + (p2 + p3);
        uint2 pk;
        pk.x = __builtin_amdgcn_perm(__float_as_uint(p1), __float_as_uint(p0), 0x07060302u);
        pk.y = __builtin_amdgcn_perm(__float_as_uint(p3), __float_as_uint(p2), 0x07060302u);
        *(uint2*)(QP + prow * QPITCH + mb * 16 + quad * 4) = pk;
    }
}

__device__ __forceinline__ void mask_diag(f32x4 (&s)[4], int qloc, int quad)
{
#pragma unroll
    for (int mb = 0; mb < 4; mb++)
#pragma unroll
        for (int r = 0; r < 4; r++)
            if (mb * 16 + quad * 4 + r > qloc) s[mb][r] = -1e30f;
}

// Issue the 4 global_load_lds for K tile [k][d] and Vt tile [d][k] of
// iteration kt_ into double-buffer half buf_.  No waits here.
#define STAGE_KV(kt_, buf_) do {                                              \
    const int _k0 = (kt_) * 64;                                               \
    const int _bo = (buf_) * 4096;                                            \
    _Pragma("unroll")                                                         \
    for (int rr = 0; rr < 2; rr++) {                                          \
        const ushort_t* gk = basek + (size_t)(_k0 + rr * 32 + srow) * C3 + csrc8; \
        GLL16(gk, Ks + _bo + rr * 2048 + tid * 8);                            \
        const ushort_t* gv = vrow + (size_t)(rr * 32 + srow) * T_LEN + _k0 + csrc8; \
        GLL16(gv, Vs + _bo + rr * 2048 + tid * 8);                            \
    }                                                                         \
} while (0)

__global__ __launch_bounds__(256) void attn_flash_mfma5(
    const ushort_t* __restrict__ qkv, const ushort_t* __restrict__ vtg,
    ushort_t* __restrict__ y)
{
    __shared__ ushort_t QP[128 * QPITCH];   // 18 KB: Q staging then P (pitch 72)
    __shared__ ushort_t Ks[2 * 64 * 64];    // 16 KB, double-buffered, XOR swizzle
    __shared__ ushort_t Vs[2 * 64 * 64];    // 16 KB, double-buffered, Vt [d][k]

    const int i = blockIdx.x;              // pair index 0..15
    const int bh = blockIdx.y;
    const int b = bh >> 4, h = bh & 15;
    const int qA0 = i * 64;
    const int qB0 = (31 - i) * 64;
    const int lastkt = 31 - i;

    const int tid = threadIdx.x;
    const int w = tid >> 6;
    const int ln = tid & 63;
    const int quad = ln >> 4;
    const int r16 = ln & 15;
    const int qloc = w * 16 + r16;
    const int prowA = qloc;
    const int prowB = 64 + qloc;

    const int srow = tid >> 3;                       // 0..31
    const int csrc8 = ((tid & 7) ^ (srow & 7)) * 8;  // swizzled source chunk
    const int cpos0 = ((quad ^ (r16 & 7))) * 8;      // s=0 read pos; s=1: ^32

    const ushort_t* baseq = qkv + (size_t)b * T_LEN * C3 + h * HDIM;
    const ushort_t* basek = baseq + C_DIM;
    const ushort_t* vrow = vtg + (size_t)bh * HDIM * T_LEN;

    // ---- issue stage of kt=0 into buffer 0 (latency overlaps Q staging) ----
    STAGE_KV(0, 0);

    // ---- stage Q: rows 0..63 = tile A, 64..127 = tile B (pitch 72) ----
#pragma unroll
    for (int it = 0; it < 4; it++) {
        int e = tid + it * 256;
        int r = e >> 3, c8 = (e & 7) * 8;
        int gq = (r < 64) ? (qA0 + r) : (qB0 + r - 64);
        *(u16x8*)(QP + r * QPITCH + c8) =
            *(const u16x8*)(baseq + (size_t)gq * C3 + c8);
    }
    __syncthreads();   // Q visible to all waves (also drains stage(0) vmcnt)

    bf16x8 aqA[2], aqB[2];
#pragma unroll
    for (int s = 0; s < 2; s++) {
        aqA[s] = *(const bf16x8*)(QP + prowA * QPITCH + s * 32 + quad * 8);
        aqB[s] = *(const bf16x8*)(QP + prowB * QPITCH + s * 32 + quad * 8);
    }

    f32x4 oA[4] = {}, oB[4] = {};
    float lA = 0.0f, lB = 0.0f;            // per-lane partials; reduced at end

    for (int kt = 0; kt <= lastkt; kt++) {
        // Single barrier per iteration: the implicit vmcnt(0) drain waits for
        // stage(kt) -- issued one full iteration ago -- and all waves' LDS
        // reads of buffer (kt-1)&1 are complete (they precede this barrier).
        __syncthreads();

        // Prefetch kt+1 into the other buffer; waited only at the NEXT barrier.
        if (kt < lastkt) STAGE_KV(kt + 1, (kt + 1) & 1);

        const int kb = (kt & 1) * 4096;

        if (kt <= i) {
            // ---- both halves active (shared ak / av frags) ----
            f32x4 sA[4] = {}, sB[4] = {};
#pragma unroll
            for (int s = 0; s < 2; s++)
#pragma unroll
                for (int mb = 0; mb < 4; mb++) {
                    const bf16x8 ak = *(const bf16x8*)(Ks + kb + (mb * 16 + r16) * 64 + (cpos0 ^ (s * 32)));
                    sA[mb] = __builtin_amdgcn_mfma_f32_16x16x32_bf16(ak, aqA[s], sA[mb], 0, 0, 0);
                    sB[mb] = __builtin_amdgcn_mfma_f32_16x16x32_bf16(ak, aqB[s], sB[mb], 0, 0, 0);
                }
            if (kt == i) mask_diag(sA, qloc, quad);
            softmax_store(sA, lA, QP, prowA, quad);
            softmax_store(sB, lB, QP, prowB, quad);
#pragma unroll
            for (int s = 0; s < 2; s++) {
                const bf16x8 bpA = *(const bf16x8*)(QP + prowA * QPITCH + s * 32 + quad * 8);
                const bf16x8 bpB = *(const bf16x8*)(QP + prowB * QPITCH + s * 32 + quad * 8);
#pragma unroll
                for (int mb = 0; mb < 4; mb++) {
                    const bf16x8 av = *(const bf16x8*)(Vs + kb + (mb * 16 + r16) * 64 + (cpos0 ^ (s * 32)));
                    oA[mb] = __builtin_amdgcn_mfma_f32_16x16x32_bf16(av, bpA, oA[mb], 0, 0, 0);
                    oB[mb] = __builtin_amdgcn_mfma_f32_16x16x32_bf16(av, bpB, oB[mb], 0, 0, 0);
                }
            }
        } else {
            // ---- B-half only ----
            f32x4 sB[4] = {};
#pragma unroll
            for (int s = 0; s < 2; s++)
#pragma unroll
                for (int mb = 0; mb < 4; mb++) {
                    const bf16x8 ak = *(const bf16x8*)(Ks + kb + (mb * 16 + r16) * 64 + (cpos0 ^ (s * 32)));
                    sB[mb] = __builtin_amdgcn_mfma_f32_16x16x32_bf16(ak, aqB[s], sB[mb], 0, 0, 0);
                }
            if (kt == lastkt) mask_diag(sB, qloc, quad);
            softmax_store(sB, lB, QP, prowB, quad);
#pragma unroll
            for (int s = 0; s < 2; s++) {
                const bf16x8 bpB = *(const bf16x8*)(QP + prowB * QPITCH + s * 32 + quad * 8);
#pragma unroll
                for (int mb = 0; mb < 4; mb++) {
                    const bf16x8 av = *(const bf16x8*)(Vs + kb + (mb * 16 + r16) * 64 + (cpos0 ^ (s * 32)));
                    oB[mb] = __builtin_amdgcn_mfma_f32_16x16x32_bf16(av, bpB, oB[mb], 0, 0, 0);
                }
            }
        }
    }

    // ---- epilogue: reduce l across the 4 lanes sharing each q, store ----
    lA += __shfl_xor(lA, 16); lA += __shfl_xor(lA, 32);
    lB += __shfl_xor(lB, 16); lB += __shfl_xor(lB, 32);
    {
        const float invA = 1.0f / lA;
        ushort_t* yp = y + ((size_t)(b * T_LEN + qA0 + qloc)) * C_DIM + h * HDIM;
#pragma unroll
        for (int mb = 0; mb < 4; mb++) {
            ushort4 o;
            o.x = f2bf(oA[mb][0] * invA);
            o.y = f2bf(oA[mb][1] * invA);
            o.z = f2bf(oA[mb][2] * invA);
            o.w = f2bf(oA[mb][3] * invA);
            *(ushort4*)(yp + mb * 16 + quad * 4) = o;
        }
    }
    {
        const float invB = 1.0f / lB;
        ushort_t* yp = y + ((size_t)(b * T_LEN + qB0 + qloc)) * C_DIM + h * HDIM;
#pragma unroll
        for (int mb = 0; mb < 4; mb++) {
            ushort4 o;
            o.x = f2bf(oB[mb][0] * invB);
            o.y = f2bf(oB[mb][1] * invB);
            o.z = f2bf(oB[mb][2] * invB);
            o.w = f2bf(oB[mb][3] * invB);
            *(ushort4*)(yp + mb * 16 + quad * 4) = o;
        }
    }
}

// ---------------------------------------------------------------------------
extern "C" void kernel_launch(void* const* d_in, const int* in_sizes, int n_in,
                              void* d_out, int out_size, void* d_ws, size_t ws_size,
                              hipStream_t stream)
{
    const float* x      = (const float*)d_in[0];
    const float* W_attn = (const float*)d_in[1];
    const float* b_attn = (const float*)d_in[2];
    const float* W_proj = (const float*)d_in[3];
    const float* b_proj = (const float*)d_in[4];
    float* out = (float*)d_out;

    const int M = 4 * T_LEN;  // 8192
    char* ws = (char*)d_ws;
    ushort_t* qkv = (ushort_t*)ws;
    ushort_t* xb  = (ushort_t*)(ws + 50331648);
    ushort_t* Wt1 = (ushort_t*)(ws + 67108864);
    ushort_t* yb  = (ushort_t*)(ws + 73400320);
    ushort_t* Wt2 = (ushort_t*)(ws + 90177536);
    ushort_t* vtg = (ushort_t*)(ws + 92274688);

    prep_inputs<<<9216, 256, 0, stream>>>(x, xb, W_attn, Wt1, W_proj, Wt2);

    // 1) qkv = x @ W_attn + b_attn  (bf16; Q slice pre-scaled by QK_SCALE)
    gemm_bt_mfma<true, true><<<dim3(C3 / 128, M / 128), 256, 0, stream>>>(
        xb, Wt1, b_attn, qkv, M, C3, C_DIM);

    transpose_v<<<dim3(T_LEN / 64, 4 * NHEAD), 256, 0, stream>>>(qkv, vtg);

    // 2) causal flash attention (paired q-tiles) -> yb bf16
    attn_flash_mfma5<<<dim3(16, 4 * NHEAD), 256, 0, stream>>>(qkv, vtg, yb);

    // 3) out = y @ W_proj + b_proj  (f32 out)
    gemm_bt_mfma<false, false><<<dim3(C_DIM / 128, M / 128), 256, 0, stream>>>(
        yb, Wt2, b_proj, out, M, C_DIM, C_DIM);
}

// Round 3
// 273.661 us; speedup vs baseline: 1.0241x; 1.0241x over previous
//
#include <hip/hip_runtime.h>
#include <math.h>

// Problem constants: B=4, T=2048, C=1024, NH=16, H=64
#define T_LEN 2048
#define C_DIM 1024
#define C3    3072
#define NHEAD 16
#define HDIM  64

typedef __attribute__((ext_vector_type(8))) __bf16 bf16x8;
typedef __attribute__((ext_vector_type(8))) unsigned short u16x8;
typedef __attribute__((ext_vector_type(4))) float f32x4;
typedef unsigned short ushort_t;

#define QK_SCALE 0.180336878f   // 1/sqrt(64) * log2(e), folded into Q

#if defined(__has_builtin)
#if __has_builtin(__builtin_amdgcn_exp2f)
#define FAST_EXP2(x) __builtin_amdgcn_exp2f(x)
#endif
#endif
#ifndef FAST_EXP2
#define FAST_EXP2(x) exp2f(x)
#endif

__device__ __forceinline__ ushort_t f2bf(float f) {
    unsigned int u = __float_as_uint(f);
    unsigned int r = (u + 0x7FFFu + ((u >> 16) & 1u)) >> 16;  // RNE
    return (ushort_t)r;
}

#define GLL16(g, l) __builtin_amdgcn_global_load_lds( \
    (const __attribute__((address_space(1))) void*)(g), \
    (__attribute__((address_space(3))) void*)(l), 16, 0, 0)

// ---------------------------------------------------------------------------
// Fused prep: x cast (blocks 0..8191), W_attn transpose (8192..8959),
// W_proj transpose (8960..9215).
// ---------------------------------------------------------------------------
__global__ __launch_bounds__(256) void prep_inputs(
    const float* __restrict__ x, ushort_t* __restrict__ xb,
    const float* __restrict__ W1, ushort_t* __restrict__ Wt1,
    const float* __restrict__ W2, ushort_t* __restrict__ Wt2)
{
    __shared__ float t[64][65];
    const int bx = blockIdx.x;
    if (bx < 8192) {
        const int i = bx * 256 + threadIdx.x;
        const float4 v = ((const float4*)x)[i];
        ushort4 o;
        o.x = f2bf(v.x); o.y = f2bf(v.y); o.z = f2bf(v.z); o.w = f2bf(v.w);
        ((ushort4*)xb)[i] = o;
        return;
    }
    const float* W; ushort_t* Wt; int N, n0, k0;
    if (bx < 8960) {
        const int tt = bx - 8192;
        W = W1; Wt = Wt1; N = C3;
        n0 = (tt % 48) * 64; k0 = (tt / 48) * 64;
    } else {
        const int tt = bx - 8960;
        W = W2; Wt = Wt2; N = C_DIM;
        n0 = (tt % 16) * 64; k0 = (tt / 16) * 64;
    }
    const int K = C_DIM;
    const int c = threadIdx.x & 63, r4 = threadIdx.x >> 6;
#pragma unroll
    for (int i = 0; i < 16; i++) {
        int r = i * 4 + r4;
        t[r][c] = W[(size_t)(k0 + r) * N + n0 + c];
    }
    __syncthreads();
#pragma unroll
    for (int i = 0; i < 16; i++) {
        int r = i * 4 + r4;
        Wt[(size_t)(n0 + r) * K + k0 + c] = f2bf(t[c][r]);
    }
}

// ---------------------------------------------------------------------------
// bf16 MFMA GEMM: 128x128 tile, BK=64, 256 threads, XOR-swizzled unpadded
// LDS staged via global_load_lds width=16. Logical chunk c of row m sits at
// position c^(m&7); frag readers use pos=(4s+quad)^(r16&7) -> uniform banks.
// ---------------------------------------------------------------------------
template <bool OUT_BF16, bool QSCALE>
__global__ __launch_bounds__(256, 3) void gemm_bt_mfma(
    const ushort_t* __restrict__ A, const ushort_t* __restrict__ Bt,
    const float* __restrict__ bias, void* __restrict__ Cv,
    int M, int N, int K)
{
    __shared__ ushort_t Alds[128 * 64];   // 16 KB
    __shared__ ushort_t Blds[128 * 64];   // 16 KB

    const int tid = threadIdx.x;
    const int m0 = blockIdx.y * 128;
    const int n0 = blockIdx.x * 128;
    const int w = tid >> 6;
    const int ln = tid & 63;
    const int quad = ln >> 4;
    const int r16 = ln & 15;
    const int wr0 = (w & 1) * 64;
    const int wc0 = (w >> 1) * 64;

    f32x4 acc[4][4] = {};

    const int srow = tid >> 3;                       // 0..31 (row within round)
    const int csrc8 = ((tid & 7) ^ (srow & 7)) * 8;  // swizzled source elem ofs
    const int sw = r16 & 7;

    for (int k0 = 0; k0 < K; k0 += 64) {
#pragma unroll
        for (int rr = 0; rr < 4; rr++) {
            const ushort_t* ga = A + (size_t)(m0 + rr * 32 + srow) * K + k0 + csrc8;
            GLL16(ga, Alds + rr * 2048 + tid * 8);
            const ushort_t* gb = Bt + (size_t)(n0 + rr * 32 + srow) * K + k0 + csrc8;
            GLL16(gb, Blds + rr * 2048 + tid * 8);
        }
        __syncthreads();

#pragma unroll
        for (int s = 0; s < 2; s++) {
            const int cpos = ((4 * s + quad) ^ sw) * 8;
            bf16x8 af[4], bfr[4];
#pragma unroll
            for (int i = 0; i < 4; i++)
                af[i] = *(const bf16x8*)(Alds + (wr0 + i * 16 + r16) * 64 + cpos);
#pragma unroll
            for (int j = 0; j < 4; j++)
                bfr[j] = *(const bf16x8*)(Blds + (wc0 + j * 16 + r16) * 64 + cpos);
#pragma unroll
            for (int i = 0; i < 4; i++)
#pragma unroll
                for (int j = 0; j < 4; j++)
                    acc[i][j] = __builtin_amdgcn_mfma_f32_16x16x32_bf16(
                        af[i], bfr[j], acc[i][j], 0, 0, 0);
        }
        __syncthreads();
    }

    const float scl = (QSCALE && n0 < C_DIM) ? QK_SCALE : 1.0f;

#pragma unroll
    for (int j = 0; j < 4; j++) {
        const int col = n0 + wc0 + j * 16 + r16;
        const float bv = bias[col];
#pragma unroll
        for (int i = 0; i < 4; i++) {
            const int rowb = m0 + wr0 + i * 16 + quad * 4;
#pragma unroll
            for (int r = 0; r < 4; r++) {
                const float v = (acc[i][j][r] + bv) * scl;
                if (OUT_BF16)
                    ((ushort_t*)Cv)[(size_t)(rowb + r) * N + col] = f2bf(v);
                else
                    ((float*)Cv)[(size_t)(rowb + r) * N + col] = v;
            }
        }
    }
}

// ---------------------------------------------------------------------------
// V pre-transpose: qkv V-slice [b][t][2C + h*64 + d] -> vtg[bh][d][t]
// ---------------------------------------------------------------------------
__global__ __launch_bounds__(256) void transpose_v(
    const ushort_t* __restrict__ qkv, ushort_t* __restrict__ vtg)
{
    __shared__ ushort_t Ts[64][72];
    const int t0 = blockIdx.x * 64;
    const int bh = blockIdx.y;
    const int b = bh >> 4, h = bh & 15;
    const ushort_t* src = qkv + (size_t)b * T_LEN * C3 + 2 * C_DIM + h * HDIM;
    const int tid = threadIdx.x;
    {
        const int r = tid >> 2, cs = (tid & 3) * 16;
        *(u16x8*)(&Ts[r][cs])     = *(const u16x8*)(src + (size_t)(t0 + r) * C3 + cs);
        *(u16x8*)(&Ts[r][cs + 8]) = *(const u16x8*)(src + (size_t)(t0 + r) * C3 + cs + 8);
    }
    __syncthreads();
    {
        const int d = tid >> 2, ts0 = (tid & 3) * 16;
        ushort_t* dst = vtg + ((size_t)bh * HDIM + d) * T_LEN + t0 + ts0;
        u16x8 o0, o1;
#pragma unroll
        for (int j = 0; j < 8; j++) o0[j] = Ts[ts0 + j][d];
#pragma unroll
        for (int j = 0; j < 8; j++) o1[j] = Ts[ts0 + 8 + j][d];
        *(u16x8*)dst = o0;
        *(u16x8*)(dst + 8) = o1;
    }
}

// ---------------------------------------------------------------------------
// MFMA flash attention v7: v5 structure (4 blocks/CU) + K double-buffer +
// covered V staging, inside a 40 KB LDS budget (160/40 = 4 blocks/CU, grid
// 1024 = exactly resident).
//   - QP shrinks 18->16 KB: pitch 64 + XOR chunk swizzle (phys chunk =
//     logical chunk ^ (row&7)) -- same scheme as Ks/Vs, frag reads reuse
//     cpos0^(s*32).
//   - per kt: top __syncthreads (implicit vmcnt(0) drains K(kt), issued a
//     FULL iteration earlier -> covered); issue V(kt) then K(kt+1);
//     QK^T+softmax cover V latency; counted s_waitcnt vmcnt(2) (K(kt+1)
//     stays in flight, never drained mid-loop) + raw s_barrier before PV.
// ---------------------------------------------------------------------------

// exp2 -> per-lane partial sum -> P store (RTZ bf16 via v_perm), swizzled.
__device__ __forceinline__ void softmax_store(
    f32x4 (&s)[4], float& lacc, ushort_t* __restrict__ QP,
    int prow, int quad, int sw)
{
#pragma unroll
    for (int mb = 0; mb < 4; mb++) {
        const float p0 = FAST_EXP2(s[mb][0]);
        const float p1 = FAST_EXP2(s[mb][1]);
        const float p2 = FAST_EXP2(s[mb][2]);
        const float p3 = FAST_EXP2(s[mb][3]);
        lacc += (p0 + p1) + (p2 + p3);
        uint2 pk;
        pk.x = __builtin_amdgcn_perm(__float_as_uint(p1), __float_as_uint(p0), 0x07060302u);
        pk.y = __builtin_amdgcn_perm(__float_as_uint(p3), __float_as_uint(p2), 0x07060302u);
        // logical elems [mb*16+quad*4 .. +3] -> chunk 2mb+(quad>>1), half (quad&1)
        *(uint2*)(QP + prow * 64 + ((2 * mb + (quad >> 1)) ^ sw) * 8 + (quad & 1) * 4) = pk;
    }
}

__device__ __forceinline__ void mask_diag(f32x4 (&s)[4], int qloc, int quad)
{
#pragma unroll
    for (int mb = 0; mb < 4; mb++)
#pragma unroll
        for (int r = 0; r < 4; r++)
            if (mb * 16 + quad * 4 + r > qloc) s[mb][r] = -1e30f;
}

// Issue the 2 global_load_lds for Vt tile [d][k] of iteration kt_. No waits.
#define STAGE_V(kt_) do {                                                     \
    const int _k0 = (kt_) * 64;                                               \
    _Pragma("unroll")                                                         \
    for (int rr = 0; rr < 2; rr++) {                                          \
        const ushort_t* gv = vrow + (size_t)(rr * 32 + srow) * T_LEN + _k0 + csrc8; \
        GLL16(gv, Vs + rr * 2048 + tid * 8);                                  \
    }                                                                         \
} while (0)

// Issue the 2 global_load_lds for K tile [k][d] of iteration kt_ into
// double-buffer half buf_. No waits.
#define STAGE_K(kt_, buf_) do {                                               \
    const int _k0 = (kt_) * 64;                                               \
    const int _bo = (buf_) * 4096;                                            \
    _Pragma("unroll")                                                         \
    for (int rr = 0; rr < 2; rr++) {                                          \
        const ushort_t* gk = basek + (size_t)(_k0 + rr * 32 + srow) * C3 + csrc8; \
        GLL16(gk, Ks + _bo + rr * 2048 + tid * 8);                            \
    }                                                                         \
} while (0)

__global__ __launch_bounds__(256) void attn_flash_mfma5(
    const ushort_t* __restrict__ qkv, const ushort_t* __restrict__ vtg,
    ushort_t* __restrict__ y)
{
    __shared__ ushort_t QP[128 * 64];     // 16 KB: Q staging then P (swizzled)
    __shared__ ushort_t Ks[2 * 64 * 64];  // 16 KB, double-buffered, XOR swizzle
    __shared__ ushort_t Vs[64 * 64];      //  8 KB, single, Vt tile [d][k]

    const int i = blockIdx.x;              // pair index 0..15
    const int bh = blockIdx.y;
    const int b = bh >> 4, h = bh & 15;
    const int qA0 = i * 64;
    const int qB0 = (31 - i) * 64;
    const int lastkt = 31 - i;

    const int tid = threadIdx.x;
    const int w = tid >> 6;
    const int ln = tid & 63;
    const int quad = ln >> 4;
    const int r16 = ln & 15;
    const int qloc = w * 16 + r16;
    const int prowA = qloc;
    const int prowB = 64 + qloc;
    const int sw = r16 & 7;

    const int srow = tid >> 3;                       // 0..31
    const int csrc8 = ((tid & 7) ^ (srow & 7)) * 8;  // swizzled source chunk
    const int cpos0 = (quad ^ sw) * 8;               // s=0 read pos; s=1: ^32

    const ushort_t* baseq = qkv + (size_t)b * T_LEN * C3 + h * HDIM;
    const ushort_t* basek = baseq + C_DIM;
    const ushort_t* vrow = vtg + (size_t)bh * HDIM * T_LEN;

    // ---- issue stage of K(0) into buffer 0 (latency overlaps Q staging) ----
    STAGE_K(0, 0);

    // ---- stage Q: rows 0..63 = tile A, 64..127 = tile B (swizzled chunks) --
#pragma unroll
    for (int it = 0; it < 4; it++) {
        int e = tid + it * 256;
        int r = e >> 3, c = e & 7;
        int gq = (r < 64) ? (qA0 + r) : (qB0 + r - 64);
        *(u16x8*)(QP + r * 64 + ((c ^ (r & 7)) * 8)) =
            *(const u16x8*)(baseq + (size_t)gq * C3 + c * 8);
    }
    __syncthreads();   // Q + K(0) visible to all waves (full drain)

    bf16x8 aqA[2], aqB[2];
#pragma unroll
    for (int s = 0; s < 2; s++) {
        aqA[s] = *(const bf16x8*)(QP + prowA * 64 + (cpos0 ^ (s * 32)));
        aqB[s] = *(const bf16x8*)(QP + prowB * 64 + (cpos0 ^ (s * 32)));
    }

    f32x4 oA[4] = {}, oB[4] = {};
    float lA = 0.0f, lB = 0.0f;            // per-lane partials; reduced at end

    for (int kt = 0; kt <= lastkt; kt++) {
        // (a) top barrier: implicit vmcnt(0) drains K(kt) (issued one full
        // iteration ago -> latency covered); closes previous V/P read windows
        // so the stages below may overwrite.
        if (kt) __syncthreads();

        STAGE_V(kt);                               // covered by QK^T+softmax
        if (kt < lastkt) STAGE_K(kt + 1, (kt + 1) & 1);  // covered by full iter

        const int kb = (kt & 1) * 4096;

        if (kt <= i) {
            // ---- both halves active (shared ak frags) ----
            f32x4 sA[4] = {}, sB[4] = {};
#pragma unroll
            for (int s = 0; s < 2; s++)
#pragma unroll
                for (int mb = 0; mb < 4; mb++) {
                    const bf16x8 ak = *(const bf16x8*)(Ks + kb + (mb * 16 + r16) * 64 + (cpos0 ^ (s * 32)));
                    sA[mb] = __builtin_amdgcn_mfma_f32_16x16x32_bf16(ak, aqA[s], sA[mb], 0, 0, 0);
                    sB[mb] = __builtin_amdgcn_mfma_f32_16x16x32_bf16(ak, aqB[s], sB[mb], 0, 0, 0);
                }
            if (kt == i) mask_diag(sA, qloc, quad);
            softmax_store(sA, lA, QP, prowA, quad, sw);
            softmax_store(sB, lB, QP, prowB, quad, sw);

            // (b) V ready: keep the 2 K(kt+1) loads in flight (counted wait).
            if (kt < lastkt) asm volatile("s_waitcnt vmcnt(2)" ::: "memory");
            else             asm volatile("s_waitcnt vmcnt(0)" ::: "memory");
            __builtin_amdgcn_s_barrier();
            __builtin_amdgcn_sched_barrier(0);

#pragma unroll
            for (int s = 0; s < 2; s++) {
                const bf16x8 bpA = *(const bf16x8*)(QP + prowA * 64 + (cpos0 ^ (s * 32)));
                const bf16x8 bpB = *(const bf16x8*)(QP + prowB * 64 + (cpos0 ^ (s * 32)));
#pragma unroll
                for (int mb = 0; mb < 4; mb++) {
                    const bf16x8 av = *(const bf16x8*)(Vs + (mb * 16 + r16) * 64 + (cpos0 ^ (s * 32)));
                    oA[mb] = __builtin_amdgcn_mfma_f32_16x16x32_bf16(av, bpA, oA[mb], 0, 0, 0);
                    oB[mb] = __builtin_amdgcn_mfma_f32_16x16x32_bf16(av, bpB, oB[mb], 0, 0, 0);
                }
            }
        } else {
            // ---- B-half only ----
            f32x4 sB[4] = {};
#pragma unroll
            for (int s = 0; s < 2; s++)
#pragma unroll
                for (int mb = 0; mb < 4; mb++) {
                    const bf16x8 ak = *(const bf16x8*)(Ks + kb + (mb * 16 + r16) * 64 + (cpos0 ^ (s * 32)));
                    sB[mb] = __builtin_amdgcn_mfma_f32_16x16x32_bf16(ak, aqB[s], sB[mb], 0, 0, 0);
                }
            if (kt == lastkt) mask_diag(sB, qloc, quad);
            softmax_store(sB, lB, QP, prowB, quad, sw);

            if (kt < lastkt) asm volatile("s_waitcnt vmcnt(2)" ::: "memory");
            else             asm volatile("s_waitcnt vmcnt(0)" ::: "memory");
            __builtin_amdgcn_s_barrier();
            __builtin_amdgcn_sched_barrier(0);

#pragma unroll
            for (int s = 0; s < 2; s++) {
                const bf16x8 bpB = *(const bf16x8*)(QP + prowB * 64 + (cpos0 ^ (s * 32)));
#pragma unroll
                for (int mb = 0; mb < 4; mb++) {
                    const bf16x8 av = *(const bf16x8*)(Vs + (mb * 16 + r16) * 64 + (cpos0 ^ (s * 32)));
                    oB[mb] = __builtin_amdgcn_mfma_f32_16x16x32_bf16(av, bpB, oB[mb], 0, 0, 0);
                }
            }
        }
    }

    // ---- epilogue: reduce l across the 4 lanes sharing each q, store ----
    lA += __shfl_xor(lA, 16); lA += __shfl_xor(lA, 32);
    lB += __shfl_xor(lB, 16); lB += __shfl_xor(lB, 32);
    {
        const float invA = 1.0f / lA;
        ushort_t* yp = y + ((size_t)(b * T_LEN + qA0 + qloc)) * C_DIM + h * HDIM;
#pragma unroll
        for (int mb = 0; mb < 4; mb++) {
            ushort4 o;
            o.x = f2bf(oA[mb][0] * invA);
            o.y = f2bf(oA[mb][1] * invA);
            o.z = f2bf(oA[mb][2] * invA);
            o.w = f2bf(oA[mb][3] * invA);
            *(ushort4*)(yp + mb * 16 + quad * 4) = o;
        }
    }
    {
        const float invB = 1.0f / lB;
        ushort_t* yp = y + ((size_t)(b * T_LEN + qB0 + qloc)) * C_DIM + h * HDIM;
#pragma unroll
        for (int mb = 0; mb < 4; mb++) {
            ushort4 o;
            o.x = f2bf(oB[mb][0] * invB);
            o.y = f2bf(oB[mb][1] * invB);
            o.z = f2bf(oB[mb][2] * invB);
            o.w = f2bf(oB[mb][3] * invB);
            *(ushort4*)(yp + mb * 16 + quad * 4) = o;
        }
    }
}

// ---------------------------------------------------------------------------
extern "C" void kernel_launch(void* const* d_in, const int* in_sizes, int n_in,
                              void* d_out, int out_size, void* d_ws, size_t ws_size,
                              hipStream_t stream)
{
    const float* x      = (const float*)d_in[0];
    const float* W_attn = (const float*)d_in[1];
    const float* b_attn = (const float*)d_in[2];
    const float* W_proj = (const float*)d_in[3];
    const float* b_proj = (const float*)d_in[4];
    float* out = (float*)d_out;

    const int M = 4 * T_LEN;  // 8192
    char* ws = (char*)d_ws;
    ushort_t* qkv = (ushort_t*)ws;
    ushort_t* xb  = (ushort_t*)(ws + 50331648);
    ushort_t* Wt1 = (ushort_t*)(ws + 67108864);
    ushort_t* yb  = (ushort_t*)(ws + 73400320);
    ushort_t* Wt2 = (ushort_t*)(ws + 90177536);
    ushort_t* vtg = (ushort_t*)(ws + 92274688);

    prep_inputs<<<9216, 256, 0, stream>>>(x, xb, W_attn, Wt1, W_proj, Wt2);

    // 1) qkv = x @ W_attn + b_attn  (bf16; Q slice pre-scaled by QK_SCALE)
    gemm_bt_mfma<true, true><<<dim3(C3 / 128, M / 128), 256, 0, stream>>>(
        xb, Wt1, b_attn, qkv, M, C3, C_DIM);

    transpose_v<<<dim3(T_LEN / 64, 4 * NHEAD), 256, 0, stream>>>(qkv, vtg);

    // 2) causal flash attention (paired q-tiles) -> yb bf16
    attn_flash_mfma5<<<dim3(16, 4 * NHEAD), 256, 0, stream>>>(qkv, vtg, yb);

    // 3) out = y @ W_proj + b_proj  (f32 out)
    gemm_bt_mfma<false, false><<<dim3(C_DIM / 128, M / 128), 256, 0, stream>>>(
        yb, Wt2, b_proj, out, M, C_DIM, C_DIM);
}

// Round 5
// 263.925 us; speedup vs baseline: 1.0619x; 1.0369x over previous
//
#include <hip/hip_runtime.h>
#include <math.h>

// Problem constants: B=4, T=2048, C=1024, NH=16, H=64
#define T_LEN 2048
#define C_DIM 1024
#define C3    3072
#define NHEAD 16
#define HDIM  64

typedef __attribute__((ext_vector_type(8))) __bf16 bf16x8;
typedef __attribute__((ext_vector_type(8))) unsigned short u16x8;
typedef __attribute__((ext_vector_type(4))) float f32x4;
typedef __attribute__((ext_vector_type(2))) unsigned int u32x2;
typedef unsigned short ushort_t;

#define QK_SCALE 0.180336878f   // 1/sqrt(64) * log2(e), folded into Q

#if defined(__has_builtin)
#if __has_builtin(__builtin_amdgcn_exp2f)
#define FAST_EXP2(x) __builtin_amdgcn_exp2f(x)
#endif
#if __has_builtin(__builtin_amdgcn_permlane32_swap) && __has_builtin(__builtin_amdgcn_permlane16_swap)
#define HAVE_PERMLANE_SWAP 1
#endif
#endif
#ifndef FAST_EXP2
#define FAST_EXP2(x) exp2f(x)
#endif

__device__ __forceinline__ ushort_t f2bf(float f) {
    unsigned int u = __float_as_uint(f);
    unsigned int r = (u + 0x7FFFu + ((u >> 16) & 1u)) >> 16;  // RNE
    return (ushort_t)r;
}

#define GLL16(g, l) __builtin_amdgcn_global_load_lds( \
    (const __attribute__((address_space(1))) void*)(g), \
    (__attribute__((address_space(3))) void*)(l), 16, 0, 0)

// ---------------------------------------------------------------------------
// Fused prep: x cast (blocks 0..8191), W_attn transpose (8192..8959),
// W_proj transpose (8960..9215).
// ---------------------------------------------------------------------------
__global__ __launch_bounds__(256) void prep_inputs(
    const float* __restrict__ x, ushort_t* __restrict__ xb,
    const float* __restrict__ W1, ushort_t* __restrict__ Wt1,
    const float* __restrict__ W2, ushort_t* __restrict__ Wt2)
{
    __shared__ float t[64][65];
    const int bx = blockIdx.x;
    if (bx < 8192) {
        const int i = bx * 256 + threadIdx.x;
        const float4 v = ((const float4*)x)[i];
        ushort4 o;
        o.x = f2bf(v.x); o.y = f2bf(v.y); o.z = f2bf(v.z); o.w = f2bf(v.w);
        ((ushort4*)xb)[i] = o;
        return;
    }
    const float* W; ushort_t* Wt; int N, n0, k0;
    if (bx < 8960) {
        const int tt = bx - 8192;
        W = W1; Wt = Wt1; N = C3;
        n0 = (tt % 48) * 64; k0 = (tt / 48) * 64;
    } else {
        const int tt = bx - 8960;
        W = W2; Wt = Wt2; N = C_DIM;
        n0 = (tt % 16) * 64; k0 = (tt / 16) * 64;
    }
    const int K = C_DIM;
    const int c = threadIdx.x & 63, r4 = threadIdx.x >> 6;
#pragma unroll
    for (int i = 0; i < 16; i++) {
        int r = i * 4 + r4;
        t[r][c] = W[(size_t)(k0 + r) * N + n0 + c];
    }
    __syncthreads();
#pragma unroll
    for (int i = 0; i < 16; i++) {
        int r = i * 4 + r4;
        Wt[(size_t)(n0 + r) * K + k0 + c] = f2bf(t[c][r]);
    }
}

// ---------------------------------------------------------------------------
// bf16 MFMA GEMM: 128x128 tile, BK=64, 256 threads, XOR-swizzled unpadded
// LDS staged via global_load_lds width=16. Logical chunk c of row m sits at
// position c^(m&7); frag readers use pos=(4s+quad)^(r16&7) -> uniform banks.
// ---------------------------------------------------------------------------
template <bool OUT_BF16, bool QSCALE>
__global__ __launch_bounds__(256, 3) void gemm_bt_mfma(
    const ushort_t* __restrict__ A, const ushort_t* __restrict__ Bt,
    const float* __restrict__ bias, void* __restrict__ Cv,
    int M, int N, int K)
{
    __shared__ ushort_t Alds[128 * 64];   // 16 KB
    __shared__ ushort_t Blds[128 * 64];   // 16 KB

    const int tid = threadIdx.x;
    const int m0 = blockIdx.y * 128;
    const int n0 = blockIdx.x * 128;
    const int w = tid >> 6;
    const int ln = tid & 63;
    const int quad = ln >> 4;
    const int r16 = ln & 15;
    const int wr0 = (w & 1) * 64;
    const int wc0 = (w >> 1) * 64;

    f32x4 acc[4][4] = {};

    const int srow = tid >> 3;                       // 0..31 (row within round)
    const int csrc8 = ((tid & 7) ^ (srow & 7)) * 8;  // swizzled source elem ofs
    const int sw = r16 & 7;

    for (int k0 = 0; k0 < K; k0 += 64) {
#pragma unroll
        for (int rr = 0; rr < 4; rr++) {
            const ushort_t* ga = A + (size_t)(m0 + rr * 32 + srow) * K + k0 + csrc8;
            GLL16(ga, Alds + rr * 2048 + tid * 8);
            const ushort_t* gb = Bt + (size_t)(n0 + rr * 32 + srow) * K + k0 + csrc8;
            GLL16(gb, Blds + rr * 2048 + tid * 8);
        }
        __syncthreads();

#pragma unroll
        for (int s = 0; s < 2; s++) {
            const int cpos = ((4 * s + quad) ^ sw) * 8;
            bf16x8 af[4], bfr[4];
#pragma unroll
            for (int i = 0; i < 4; i++)
                af[i] = *(const bf16x8*)(Alds + (wr0 + i * 16 + r16) * 64 + cpos);
#pragma unroll
            for (int j = 0; j < 4; j++)
                bfr[j] = *(const bf16x8*)(Blds + (wc0 + j * 16 + r16) * 64 + cpos);
#pragma unroll
            for (int i = 0; i < 4; i++)
#pragma unroll
                for (int j = 0; j < 4; j++)
                    acc[i][j] = __builtin_amdgcn_mfma_f32_16x16x32_bf16(
                        af[i], bfr[j], acc[i][j], 0, 0, 0);
        }
        __syncthreads();
    }

    const float scl = (QSCALE && n0 < C_DIM) ? QK_SCALE : 1.0f;

#pragma unroll
    for (int j = 0; j < 4; j++) {
        const int col = n0 + wc0 + j * 16 + r16;
        const float bv = bias[col];
#pragma unroll
        for (int i = 0; i < 4; i++) {
            const int rowb = m0 + wr0 + i * 16 + quad * 4;
#pragma unroll
            for (int r = 0; r < 4; r++) {
                const float v = (acc[i][j][r] + bv) * scl;
                if (OUT_BF16)
                    ((ushort_t*)Cv)[(size_t)(rowb + r) * N + col] = f2bf(v);
                else
                    ((float*)Cv)[(size_t)(rowb + r) * N + col] = v;
            }
        }
    }
}

// ---------------------------------------------------------------------------
// V pre-transpose: qkv V-slice [b][t][2C + h*64 + d] -> vtg[bh][d][t]
// ---------------------------------------------------------------------------
__global__ __launch_bounds__(256) void transpose_v(
    const ushort_t* __restrict__ qkv, ushort_t* __restrict__ vtg)
{
    __shared__ ushort_t Ts[64][72];
    const int t0 = blockIdx.x * 64;
    const int bh = blockIdx.y;
    const int b = bh >> 4, h = bh & 15;
    const ushort_t* src = qkv + (size_t)b * T_LEN * C3 + 2 * C_DIM + h * HDIM;
    const int tid = threadIdx.x;
    {
        const int r = tid >> 2, cs = (tid & 3) * 16;
        *(u16x8*)(&Ts[r][cs])     = *(const u16x8*)(src + (size_t)(t0 + r) * C3 + cs);
        *(u16x8*)(&Ts[r][cs + 8]) = *(const u16x8*)(src + (size_t)(t0 + r) * C3 + cs + 8);
    }
    __syncthreads();
    {
        const int d = tid >> 2, ts0 = (tid & 3) * 16;
        ushort_t* dst = vtg + ((size_t)bh * HDIM + d) * T_LEN + t0 + ts0;
        u16x8 o0, o1;
#pragma unroll
        for (int j = 0; j < 8; j++) o0[j] = Ts[ts0 + j][d];
#pragma unroll
        for (int j = 0; j < 8; j++) o1[j] = Ts[ts0 + 8 + j][d];
        *(u16x8*)dst = o0;
        *(u16x8*)(dst + 8) = o1;
    }
}

// ---------------------------------------------------------------------------
// MFMA flash attention v8b: in-register P exchange (no P LDS round-trip),
// no QP buffer (Q frags loaded directly from global), K AND V double-buffered,
// ONE barrier per iteration. LDS = 32 KB.
//
// QK^T (swapped) leaves sA[mb][r] = P[q=qloc][k=16mb+4*quad+r]; after bf16
// pack, pk[mb][u] = P pair k=16mb+4*quad+2u(,+1). PV B-frag needs uint u' at
// quad qt = P[k=32*s2+8*qt+2u']. With A=pk[2s2][u], B=pk[2s2+1][u]
// (quad-vectors A=[A0..A3], B=[B0..B3]):
//   need out1=[A0,A2,B0,B2] (-> u'=u slot), out2=[A1,A3,B1,B3] (-> u'=u+2).
// HW semantics (CDNA4):
//   permlane32_swap(vdst=X,src0=Y): X'=[X0,X1,Y0,Y1], Y'=[X2,X3,Y2,Y3]
//   permlane16_swap(vdst=X,src0=Y): X'=[X0,Y0,X2,Y2], Y'=[X1,Y1,X3,Y3]
// Compose with vdst=A, src0=B:
//   swap32: A1=[A0,A1,B0,B1], B1=[A2,A3,B2,B3]
//   swap16: A2=[A0,A2,B0,B2]=out1 ✓   B2=[A1,A3,B1,B3]=out2 ✓
// ---------------------------------------------------------------------------

__device__ __forceinline__ void mask_diag(f32x4 (&s)[4], int qloc, int quad)
{
#pragma unroll
    for (int mb = 0; mb < 4; mb++)
#pragma unroll
        for (int r = 0; r < 4; r++)
            if (mb * 16 + quad * 4 + r > qloc) s[mb][r] = -1e30f;
}

// exp2 -> per-lane partial sum -> pack bf16 (RTZ) -> cross-quad permlane
// exchange -> PV B-frags. No LDS.
__device__ __forceinline__ void softmax_exchange(
    f32x4 (&s)[4], float& lacc, bf16x8 (&bp)[2])
{
    unsigned int pk[4][2];
#pragma unroll
    for (int mb = 0; mb < 4; mb++) {
        const float p0 = FAST_EXP2(s[mb][0]);
        const float p1 = FAST_EXP2(s[mb][1]);
        const float p2 = FAST_EXP2(s[mb][2]);
        const float p3 = FAST_EXP2(s[mb][3]);
        lacc += (p0 + p1) + (p2 + p3);
        pk[mb][0] = __builtin_amdgcn_perm(__float_as_uint(p1), __float_as_uint(p0), 0x07060302u);
        pk[mb][1] = __builtin_amdgcn_perm(__float_as_uint(p3), __float_as_uint(p2), 0x07060302u);
    }
#pragma unroll
    for (int s2 = 0; s2 < 2; s2++) {
        uint4 t;
#pragma unroll
        for (int u = 0; u < 2; u++) {
            unsigned int A = pk[2 * s2][u], B = pk[2 * s2 + 1][u];
            unsigned int out1, out2;
#ifdef HAVE_PERMLANE_SWAP
            u32x2 r1 = __builtin_amdgcn_permlane32_swap(A, B, false, false);
            u32x2 r2 = __builtin_amdgcn_permlane16_swap(r1.x, r1.y, false, false);
            out1 = r2.x; out2 = r2.y;
#else
            asm volatile("s_nop 1\n\t"
                         "v_permlane32_swap_b32 %0, %1\n\t"
                         "s_nop 1\n\t"
                         "v_permlane16_swap_b32 %0, %1"
                         : "+v"(A), "+v"(B));
            out1 = A; out2 = B;
#endif
            if (u == 0) { t.x = out1; t.z = out2; }
            else        { t.y = out1; t.w = out2; }
        }
        bp[s2] = *(bf16x8*)&t;
    }
}

// Issue the 2 global_load_lds for K tile [k][d] of iteration kt_ into
// double-buffer half buf_. No waits.
#define STAGE_K(kt_, buf_) do {                                               \
    const int _k0 = (kt_) * 64;                                               \
    const int _bo = (buf_) * 4096;                                            \
    _Pragma("unroll")                                                         \
    for (int rr = 0; rr < 2; rr++) {                                          \
        const ushort_t* gk = basek + (size_t)(_k0 + rr * 32 + srow) * C3 + csrc8; \
        GLL16(gk, Ks + _bo + rr * 2048 + tid * 8);                            \
    }                                                                         \
} while (0)

// Same for Vt tile [d][k].
#define STAGE_V(kt_, buf_) do {                                               \
    const int _k0 = (kt_) * 64;                                               \
    const int _bo = (buf_) * 4096;                                            \
    _Pragma("unroll")                                                         \
    for (int rr = 0; rr < 2; rr++) {                                          \
        const ushort_t* gv = vrow + (size_t)(rr * 32 + srow) * T_LEN + _k0 + csrc8; \
        GLL16(gv, Vs + _bo + rr * 2048 + tid * 8);                            \
    }                                                                         \
} while (0)

__global__ __launch_bounds__(256, 4) void attn_flash_mfma5(
    const ushort_t* __restrict__ qkv, const ushort_t* __restrict__ vtg,
    ushort_t* __restrict__ y)
{
    __shared__ ushort_t Ks[2 * 64 * 64];  // 16 KB, double-buffered, XOR swizzle
    __shared__ ushort_t Vs[2 * 64 * 64];  // 16 KB, double-buffered, Vt [d][k]

    const int i = blockIdx.x;              // pair index 0..15
    const int bh = blockIdx.y;
    const int b = bh >> 4, h = bh & 15;
    const int qA0 = i * 64;
    const int qB0 = (31 - i) * 64;
    const int lastkt = 31 - i;

    const int tid = threadIdx.x;
    const int w = tid >> 6;
    const int ln = tid & 63;
    const int quad = ln >> 4;
    const int r16 = ln & 15;
    const int qloc = w * 16 + r16;
    const int sw = r16 & 7;

    const int srow = tid >> 3;                       // 0..31
    const int csrc8 = ((tid & 7) ^ (srow & 7)) * 8;  // swizzled source chunk
    const int cpos0 = (quad ^ sw) * 8;               // s=0 read pos; s=1: ^32

    const ushort_t* baseq = qkv + (size_t)b * T_LEN * C3 + h * HDIM;
    const ushort_t* basek = baseq + C_DIM;
    const ushort_t* vrow = vtg + (size_t)bh * HDIM * T_LEN;

    // ---- stage K(0)/V(0) into buffer 0; Q frags straight from global ----
    STAGE_K(0, 0);
    STAGE_V(0, 0);

    bf16x8 aqA[2], aqB[2];
#pragma unroll
    for (int s = 0; s < 2; s++) {
        aqA[s] = *(const bf16x8*)(baseq + (size_t)(qA0 + qloc) * C3 + s * 32 + quad * 8);
        aqB[s] = *(const bf16x8*)(baseq + (size_t)(qB0 + qloc) * C3 + s * 32 + quad * 8);
    }

    f32x4 oA[4] = {}, oB[4] = {};
    float lA = 0.0f, lB = 0.0f;            // per-lane partials; reduced at end

    for (int kt = 0; kt <= lastkt; kt++) {
        // Single barrier per iteration: its implicit vmcnt(0) drains
        // K/V(kt) -- staged one full iteration ago (covered) -- and its
        // lgkmcnt(0) closes all reads of the buffer being overwritten below.
        __syncthreads();

        if (kt < lastkt) {
            STAGE_K(kt + 1, (kt + 1) & 1);
            STAGE_V(kt + 1, (kt + 1) & 1);
        }

        const int kb = (kt & 1) * 4096;

        if (kt <= i) {
            // ---- both halves active (shared ak / av frags) ----
            f32x4 sA[4] = {}, sB[4] = {};
#pragma unroll
            for (int s = 0; s < 2; s++)
#pragma unroll
                for (int mb = 0; mb < 4; mb++) {
                    const bf16x8 ak = *(const bf16x8*)(Ks + kb + (mb * 16 + r16) * 64 + (cpos0 ^ (s * 32)));
                    sA[mb] = __builtin_amdgcn_mfma_f32_16x16x32_bf16(ak, aqA[s], sA[mb], 0, 0, 0);
                    sB[mb] = __builtin_amdgcn_mfma_f32_16x16x32_bf16(ak, aqB[s], sB[mb], 0, 0, 0);
                }
            if (kt == i) mask_diag(sA, qloc, quad);
            bf16x8 bpA[2], bpB[2];
            softmax_exchange(sA, lA, bpA);
            softmax_exchange(sB, lB, bpB);
#pragma unroll
            for (int s = 0; s < 2; s++)
#pragma unroll
                for (int mb = 0; mb < 4; mb++) {
                    const bf16x8 av = *(const bf16x8*)(Vs + kb + (mb * 16 + r16) * 64 + (cpos0 ^ (s * 32)));
                    oA[mb] = __builtin_amdgcn_mfma_f32_16x16x32_bf16(av, bpA[s], oA[mb], 0, 0, 0);
                    oB[mb] = __builtin_amdgcn_mfma_f32_16x16x32_bf16(av, bpB[s], oB[mb], 0, 0, 0);
                }
        } else {
            // ---- B-half only ----
            f32x4 sB[4] = {};
#pragma unroll
            for (int s = 0; s < 2; s++)
#pragma unroll
                for (int mb = 0; mb < 4; mb++) {
                    const bf16x8 ak = *(const bf16x8*)(Ks + kb + (mb * 16 + r16) * 64 + (cpos0 ^ (s * 32)));
                    sB[mb] = __builtin_amdgcn_mfma_f32_16x16x32_bf16(ak, aqB[s], sB[mb], 0, 0, 0);
                }
            if (kt == lastkt) mask_diag(sB, qloc, quad);
            bf16x8 bpB[2];
            softmax_exchange(sB, lB, bpB);
#pragma unroll
            for (int s = 0; s < 2; s++)
#pragma unroll
                for (int mb = 0; mb < 4; mb++) {
                    const bf16x8 av = *(const bf16x8*)(Vs + kb + (mb * 16 + r16) * 64 + (cpos0 ^ (s * 32)));
                    oB[mb] = __builtin_amdgcn_mfma_f32_16x16x32_bf16(av, bpB[s], oB[mb], 0, 0, 0);
                }
        }
    }

    // ---- epilogue: reduce l across the 4 lanes sharing each q, store ----
    lA += __shfl_xor(lA, 16); lA += __shfl_xor(lA, 32);
    lB += __shfl_xor(lB, 16); lB += __shfl_xor(lB, 32);
    {
        const float invA = 1.0f / lA;
        ushort_t* yp = y + ((size_t)(b * T_LEN + qA0 + qloc)) * C_DIM + h * HDIM;
#pragma unroll
        for (int mb = 0; mb < 4; mb++) {
            ushort4 o;
            o.x = f2bf(oA[mb][0] * invA);
            o.y = f2bf(oA[mb][1] * invA);
            o.z = f2bf(oA[mb][2] * invA);
            o.w = f2bf(oA[mb][3] * invA);
            *(ushort4*)(yp + mb * 16 + quad * 4) = o;
        }
    }
    {
        const float invB = 1.0f / lB;
        ushort_t* yp = y + ((size_t)(b * T_LEN + qB0 + qloc)) * C_DIM + h * HDIM;
#pragma unroll
        for (int mb = 0; mb < 4; mb++) {
            ushort4 o;
            o.x = f2bf(oB[mb][0] * invB);
            o.y = f2bf(oB[mb][1] * invB);
            o.z = f2bf(oB[mb][2] * invB);
            o.w = f2bf(oB[mb][3] * invB);
            *(ushort4*)(yp + mb * 16 + quad * 4) = o;
        }
    }
}

// ---------------------------------------------------------------------------
extern "C" void kernel_launch(void* const* d_in, const int* in_sizes, int n_in,
                              void* d_out, int out_size, void* d_ws, size_t ws_size,
                              hipStream_t stream)
{
    const float* x      = (const float*)d_in[0];
    const float* W_attn = (const float*)d_in[1];
    const float* b_attn = (const float*)d_in[2];
    const float* W_proj = (const float*)d_in[3];
    const float* b_proj = (const float*)d_in[4];
    float* out = (float*)d_out;

    const int M = 4 * T_LEN;  // 8192
    char* ws = (char*)d_ws;
    ushort_t* qkv = (ushort_t*)ws;
    ushort_t* xb  = (ushort_t*)(ws + 50331648);
    ushort_t* Wt1 = (ushort_t*)(ws + 67108864);
    ushort_t* yb  = (ushort_t*)(ws + 73400320);
    ushort_t* Wt2 = (ushort_t*)(ws + 90177536);
    ushort_t* vtg = (ushort_t*)(ws + 92274688);

    prep_inputs<<<9216, 256, 0, stream>>>(x, xb, W_attn, Wt1, W_proj, Wt2);

    // 1) qkv = x @ W_attn + b_attn  (bf16; Q slice pre-scaled by QK_SCALE)
    gemm_bt_mfma<true, true><<<dim3(C3 / 128, M / 128), 256, 0, stream>>>(
        xb, Wt1, b_attn, qkv, M, C3, C_DIM);

    transpose_v<<<dim3(T_LEN / 64, 4 * NHEAD), 256, 0, stream>>>(qkv, vtg);

    // 2) causal flash attention (paired q-tiles) -> yb bf16
    attn_flash_mfma5<<<dim3(16, 4 * NHEAD), 256, 0, stream>>>(qkv, vtg, yb);

    // 3) out = y @ W_proj + b_proj  (f32 out)
    gemm_bt_mfma<false, false><<<dim3(C_DIM / 128, M / 128), 256, 0, stream>>>(
        yb, Wt2, b_proj, out, M, C_DIM, C_DIM);
}

// Round 6
// 255.473 us; speedup vs baseline: 1.0970x; 1.0331x over previous
//
#include <hip/hip_runtime.h>
#include <math.h>

// Problem constants: B=4, T=2048, C=1024, NH=16, H=64
#define T_LEN 2048
#define C_DIM 1024
#define C3    3072
#define NHEAD 16
#define HDIM  64

typedef __attribute__((ext_vector_type(8))) __bf16 bf16x8;
typedef __attribute__((ext_vector_type(8))) unsigned short u16x8;
typedef __attribute__((ext_vector_type(4))) float f32x4;
typedef __attribute__((ext_vector_type(2))) unsigned int u32x2;
typedef unsigned short ushort_t;

#define QK_SCALE 0.180336878f   // 1/sqrt(64) * log2(e), folded into Q

#if defined(__has_builtin)
#if __has_builtin(__builtin_amdgcn_exp2f)
#define FAST_EXP2(x) __builtin_amdgcn_exp2f(x)
#endif
#if __has_builtin(__builtin_amdgcn_permlane32_swap) && __has_builtin(__builtin_amdgcn_permlane16_swap)
#define HAVE_PERMLANE_SWAP 1
#endif
#endif
#ifndef FAST_EXP2
#define FAST_EXP2(x) exp2f(x)
#endif

__device__ __forceinline__ ushort_t f2bf(float f) {
    unsigned int u = __float_as_uint(f);
    unsigned int r = (u + 0x7FFFu + ((u >> 16) & 1u)) >> 16;  // RNE
    return (ushort_t)r;
}

#define GLL16(g, l) __builtin_amdgcn_global_load_lds( \
    (const __attribute__((address_space(1))) void*)(g), \
    (__attribute__((address_space(3))) void*)(l), 16, 0, 0)

// ---------------------------------------------------------------------------
// Fused prep: x cast (blocks 0..8191), W_attn transpose (8192..8959),
// W_proj transpose (8960..9215).
// ---------------------------------------------------------------------------
__global__ __launch_bounds__(256) void prep_inputs(
    const float* __restrict__ x, ushort_t* __restrict__ xb,
    const float* __restrict__ W1, ushort_t* __restrict__ Wt1,
    const float* __restrict__ W2, ushort_t* __restrict__ Wt2)
{
    __shared__ float t[64][65];
    const int bx = blockIdx.x;
    if (bx < 8192) {
        const int i = bx * 256 + threadIdx.x;
        const float4 v = ((const float4*)x)[i];
        ushort4 o;
        o.x = f2bf(v.x); o.y = f2bf(v.y); o.z = f2bf(v.z); o.w = f2bf(v.w);
        ((ushort4*)xb)[i] = o;
        return;
    }
    const float* W; ushort_t* Wt; int N, n0, k0;
    if (bx < 8960) {
        const int tt = bx - 8192;
        W = W1; Wt = Wt1; N = C3;
        n0 = (tt % 48) * 64; k0 = (tt / 48) * 64;
    } else {
        const int tt = bx - 8960;
        W = W2; Wt = Wt2; N = C_DIM;
        n0 = (tt % 16) * 64; k0 = (tt / 16) * 64;
    }
    const int K = C_DIM;
    const int c = threadIdx.x & 63, r4 = threadIdx.x >> 6;
#pragma unroll
    for (int i = 0; i < 16; i++) {
        int r = i * 4 + r4;
        t[r][c] = W[(size_t)(k0 + r) * N + n0 + c];
    }
    __syncthreads();
#pragma unroll
    for (int i = 0; i < 16; i++) {
        int r = i * 4 + r4;
        Wt[(size_t)(n0 + r) * K + k0 + c] = f2bf(t[c][r]);
    }
}

// ---------------------------------------------------------------------------
// bf16 MFMA GEMM: 128x128 tile, BK=64, 256 threads, XOR-swizzled unpadded
// LDS staged via global_load_lds width=16. Logical chunk c of row m sits at
// position c^(m&7); frag readers use pos=(4s+quad)^(r16&7) -> uniform banks.
// ---------------------------------------------------------------------------
template <bool OUT_BF16, bool QSCALE>
__global__ __launch_bounds__(256, 3) void gemm_bt_mfma(
    const ushort_t* __restrict__ A, const ushort_t* __restrict__ Bt,
    const float* __restrict__ bias, void* __restrict__ Cv,
    int M, int N, int K)
{
    __shared__ ushort_t Alds[128 * 64];   // 16 KB
    __shared__ ushort_t Blds[128 * 64];   // 16 KB

    const int tid = threadIdx.x;
    const int m0 = blockIdx.y * 128;
    const int n0 = blockIdx.x * 128;
    const int w = tid >> 6;
    const int ln = tid & 63;
    const int quad = ln >> 4;
    const int r16 = ln & 15;
    const int wr0 = (w & 1) * 64;
    const int wc0 = (w >> 1) * 64;

    f32x4 acc[4][4] = {};

    const int srow = tid >> 3;                       // 0..31 (row within round)
    const int csrc8 = ((tid & 7) ^ (srow & 7)) * 8;  // swizzled source elem ofs
    const int sw = r16 & 7;

    for (int k0 = 0; k0 < K; k0 += 64) {
#pragma unroll
        for (int rr = 0; rr < 4; rr++) {
            const ushort_t* ga = A + (size_t)(m0 + rr * 32 + srow) * K + k0 + csrc8;
            GLL16(ga, Alds + rr * 2048 + tid * 8);
            const ushort_t* gb = Bt + (size_t)(n0 + rr * 32 + srow) * K + k0 + csrc8;
            GLL16(gb, Blds + rr * 2048 + tid * 8);
        }
        __syncthreads();

#pragma unroll
        for (int s = 0; s < 2; s++) {
            const int cpos = ((4 * s + quad) ^ sw) * 8;
            bf16x8 af[4], bfr[4];
#pragma unroll
            for (int i = 0; i < 4; i++)
                af[i] = *(const bf16x8*)(Alds + (wr0 + i * 16 + r16) * 64 + cpos);
#pragma unroll
            for (int j = 0; j < 4; j++)
                bfr[j] = *(const bf16x8*)(Blds + (wc0 + j * 16 + r16) * 64 + cpos);
#pragma unroll
            for (int i = 0; i < 4; i++)
#pragma unroll
                for (int j = 0; j < 4; j++)
                    acc[i][j] = __builtin_amdgcn_mfma_f32_16x16x32_bf16(
                        af[i], bfr[j], acc[i][j], 0, 0, 0);
        }
        __syncthreads();
    }

    const float scl = (QSCALE && n0 < C_DIM) ? QK_SCALE : 1.0f;

#pragma unroll
    for (int j = 0; j < 4; j++) {
        const int col = n0 + wc0 + j * 16 + r16;
        const float bv = bias[col];
#pragma unroll
        for (int i = 0; i < 4; i++) {
            const int rowb = m0 + wr0 + i * 16 + quad * 4;
#pragma unroll
            for (int r = 0; r < 4; r++) {
                const float v = (acc[i][j][r] + bv) * scl;
                if (OUT_BF16)
                    ((ushort_t*)Cv)[(size_t)(rowb + r) * N + col] = f2bf(v);
                else
                    ((float*)Cv)[(size_t)(rowb + r) * N + col] = v;
            }
        }
    }
}

// ---------------------------------------------------------------------------
// V pre-transpose: qkv V-slice [b][t][2C + h*64 + d] -> vtg[bh][d][t]
// ---------------------------------------------------------------------------
__global__ __launch_bounds__(256) void transpose_v(
    const ushort_t* __restrict__ qkv, ushort_t* __restrict__ vtg)
{
    __shared__ ushort_t Ts[64][72];
    const int t0 = blockIdx.x * 64;
    const int bh = blockIdx.y;
    const int b = bh >> 4, h = bh & 15;
    const ushort_t* src = qkv + (size_t)b * T_LEN * C3 + 2 * C_DIM + h * HDIM;
    const int tid = threadIdx.x;
    {
        const int r = tid >> 2, cs = (tid & 3) * 16;
        *(u16x8*)(&Ts[r][cs])     = *(const u16x8*)(src + (size_t)(t0 + r) * C3 + cs);
        *(u16x8*)(&Ts[r][cs + 8]) = *(const u16x8*)(src + (size_t)(t0 + r) * C3 + cs + 8);
    }
    __syncthreads();
    {
        const int d = tid >> 2, ts0 = (tid & 3) * 16;
        ushort_t* dst = vtg + ((size_t)bh * HDIM + d) * T_LEN + t0 + ts0;
        u16x8 o0, o1;
#pragma unroll
        for (int j = 0; j < 8; j++) o0[j] = Ts[ts0 + j][d];
#pragma unroll
        for (int j = 0; j < 8; j++) o1[j] = Ts[ts0 + 8 + j][d];
        *(u16x8*)dst = o0;
        *(u16x8*)(dst + 8) = o1;
    }
}

// ---------------------------------------------------------------------------
// MFMA flash attention v9: v8b (in-register P exchange, K+V double-buffered,
// one barrier/iter, 32 KB LDS) + head-clustered XCD swizzle.
//
// Swizzle: assuming round-robin bid%8 -> XCD dispatch, decompose
//   xcd = bid&7, k = bid>>3, i = k>>3 (pair 0..15), bh = xcd*8 + (k&7).
// All 16 pair-blocks of a head land on ONE XCD: per-XCD K/V working set =
// 8 heads x 512 KB = 4 MB = L2 size, 16x reuse -> staging hits L2 instead of
// HBM (FETCH was 2.7x ideal in v8b). Also mixes i (block lengths) per CU.
// Bijective; wrong-XCD-model only costs perf, never correctness.
// ---------------------------------------------------------------------------

__device__ __forceinline__ void mask_diag(f32x4 (&s)[4], int qloc, int quad)
{
#pragma unroll
    for (int mb = 0; mb < 4; mb++)
#pragma unroll
        for (int r = 0; r < 4; r++)
            if (mb * 16 + quad * 4 + r > qloc) s[mb][r] = -1e30f;
}

// exp2 -> per-lane partial sum -> pack bf16 (RTZ) -> cross-quad permlane
// exchange -> PV B-frags. No LDS.
__device__ __forceinline__ void softmax_exchange(
    f32x4 (&s)[4], float& lacc, bf16x8 (&bp)[2])
{
    unsigned int pk[4][2];
#pragma unroll
    for (int mb = 0; mb < 4; mb++) {
        const float p0 = FAST_EXP2(s[mb][0]);
        const float p1 = FAST_EXP2(s[mb][1]);
        const float p2 = FAST_EXP2(s[mb][2]);
        const float p3 = FAST_EXP2(s[mb][3]);
        lacc += (p0 + p1) + (p2 + p3);
        pk[mb][0] = __builtin_amdgcn_perm(__float_as_uint(p1), __float_as_uint(p0), 0x07060302u);
        pk[mb][1] = __builtin_amdgcn_perm(__float_as_uint(p3), __float_as_uint(p2), 0x07060302u);
    }
#pragma unroll
    for (int s2 = 0; s2 < 2; s2++) {
        uint4 t;
#pragma unroll
        for (int u = 0; u < 2; u++) {
            unsigned int A = pk[2 * s2][u], B = pk[2 * s2 + 1][u];
            unsigned int out1, out2;
#ifdef HAVE_PERMLANE_SWAP
            u32x2 r1 = __builtin_amdgcn_permlane32_swap(A, B, false, false);
            u32x2 r2 = __builtin_amdgcn_permlane16_swap(r1.x, r1.y, false, false);
            out1 = r2.x; out2 = r2.y;
#else
            asm volatile("s_nop 1\n\t"
                         "v_permlane32_swap_b32 %0, %1\n\t"
                         "s_nop 1\n\t"
                         "v_permlane16_swap_b32 %0, %1"
                         : "+v"(A), "+v"(B));
            out1 = A; out2 = B;
#endif
            if (u == 0) { t.x = out1; t.z = out2; }
            else        { t.y = out1; t.w = out2; }
        }
        bp[s2] = *(bf16x8*)&t;
    }
}

// Issue the 2 global_load_lds for K tile [k][d] of iteration kt_ into
// double-buffer half buf_. No waits.
#define STAGE_K(kt_, buf_) do {                                               \
    const int _k0 = (kt_) * 64;                                               \
    const int _bo = (buf_) * 4096;                                            \
    _Pragma("unroll")                                                         \
    for (int rr = 0; rr < 2; rr++) {                                          \
        const ushort_t* gk = basek + (size_t)(_k0 + rr * 32 + srow) * C3 + csrc8; \
        GLL16(gk, Ks + _bo + rr * 2048 + tid * 8);                            \
    }                                                                         \
} while (0)

// Same for Vt tile [d][k].
#define STAGE_V(kt_, buf_) do {                                               \
    const int _k0 = (kt_) * 64;                                               \
    const int _bo = (buf_) * 4096;                                            \
    _Pragma("unroll")                                                         \
    for (int rr = 0; rr < 2; rr++) {                                          \
        const ushort_t* gv = vrow + (size_t)(rr * 32 + srow) * T_LEN + _k0 + csrc8; \
        GLL16(gv, Vs + _bo + rr * 2048 + tid * 8);                            \
    }                                                                         \
} while (0)

__global__ __launch_bounds__(256, 4) void attn_flash_mfma5(
    const ushort_t* __restrict__ qkv, const ushort_t* __restrict__ vtg,
    ushort_t* __restrict__ y)
{
    __shared__ ushort_t Ks[2 * 64 * 64];  // 16 KB, double-buffered, XOR swizzle
    __shared__ ushort_t Vs[2 * 64 * 64];  // 16 KB, double-buffered, Vt [d][k]

    // ---- head-clustered XCD swizzle (see header comment) ----
    const int bid = blockIdx.x;            // 0..1023
    const int i = (bid >> 3) >> 3;         // pair index 0..15
    const int bh = (bid & 7) * 8 + ((bid >> 3) & 7);
    const int b = bh >> 4, h = bh & 15;
    const int qA0 = i * 64;
    const int qB0 = (31 - i) * 64;
    const int lastkt = 31 - i;

    const int tid = threadIdx.x;
    const int w = tid >> 6;
    const int ln = tid & 63;
    const int quad = ln >> 4;
    const int r16 = ln & 15;
    const int qloc = w * 16 + r16;
    const int sw = r16 & 7;

    const int srow = tid >> 3;                       // 0..31
    const int csrc8 = ((tid & 7) ^ (srow & 7)) * 8;  // swizzled source chunk
    const int cpos0 = (quad ^ sw) * 8;               // s=0 read pos; s=1: ^32

    const ushort_t* baseq = qkv + (size_t)b * T_LEN * C3 + h * HDIM;
    const ushort_t* basek = baseq + C_DIM;
    const ushort_t* vrow = vtg + (size_t)bh * HDIM * T_LEN;

    // ---- stage K(0)/V(0) into buffer 0; Q frags straight from global ----
    STAGE_K(0, 0);
    STAGE_V(0, 0);

    bf16x8 aqA[2], aqB[2];
#pragma unroll
    for (int s = 0; s < 2; s++) {
        aqA[s] = *(const bf16x8*)(baseq + (size_t)(qA0 + qloc) * C3 + s * 32 + quad * 8);
        aqB[s] = *(const bf16x8*)(baseq + (size_t)(qB0 + qloc) * C3 + s * 32 + quad * 8);
    }

    f32x4 oA[4] = {}, oB[4] = {};
    float lA = 0.0f, lB = 0.0f;            // per-lane partials; reduced at end

    for (int kt = 0; kt <= lastkt; kt++) {
        // Single barrier per iteration: its implicit vmcnt(0) drains
        // K/V(kt) -- staged one full iteration ago (covered) -- and its
        // lgkmcnt(0) closes all reads of the buffer being overwritten below.
        __syncthreads();

        if (kt < lastkt) {
            STAGE_K(kt + 1, (kt + 1) & 1);
            STAGE_V(kt + 1, (kt + 1) & 1);
        }

        const int kb = (kt & 1) * 4096;

        if (kt <= i) {
            // ---- both halves active (shared ak / av frags) ----
            f32x4 sA[4] = {}, sB[4] = {};
#pragma unroll
            for (int s = 0; s < 2; s++)
#pragma unroll
                for (int mb = 0; mb < 4; mb++) {
                    const bf16x8 ak = *(const bf16x8*)(Ks + kb + (mb * 16 + r16) * 64 + (cpos0 ^ (s * 32)));
                    sA[mb] = __builtin_amdgcn_mfma_f32_16x16x32_bf16(ak, aqA[s], sA[mb], 0, 0, 0);
                    sB[mb] = __builtin_amdgcn_mfma_f32_16x16x32_bf16(ak, aqB[s], sB[mb], 0, 0, 0);
                }
            if (kt == i) mask_diag(sA, qloc, quad);
            bf16x8 bpA[2], bpB[2];
            softmax_exchange(sA, lA, bpA);
            softmax_exchange(sB, lB, bpB);
#pragma unroll
            for (int s = 0; s < 2; s++)
#pragma unroll
                for (int mb = 0; mb < 4; mb++) {
                    const bf16x8 av = *(const bf16x8*)(Vs + kb + (mb * 16 + r16) * 64 + (cpos0 ^ (s * 32)));
                    oA[mb] = __builtin_amdgcn_mfma_f32_16x16x32_bf16(av, bpA[s], oA[mb], 0, 0, 0);
                    oB[mb] = __builtin_amdgcn_mfma_f32_16x16x32_bf16(av, bpB[s], oB[mb], 0, 0, 0);
                }
        } else {
            // ---- B-half only ----
            f32x4 sB[4] = {};
#pragma unroll
            for (int s = 0; s < 2; s++)
#pragma unroll
                for (int mb = 0; mb < 4; mb++) {
                    const bf16x8 ak = *(const bf16x8*)(Ks + kb + (mb * 16 + r16) * 64 + (cpos0 ^ (s * 32)));
                    sB[mb] = __builtin_amdgcn_mfma_f32_16x16x32_bf16(ak, aqB[s], sB[mb], 0, 0, 0);
                }
            if (kt == lastkt) mask_diag(sB, qloc, quad);
            bf16x8 bpB[2];
            softmax_exchange(sB, lB, bpB);
#pragma unroll
            for (int s = 0; s < 2; s++)
#pragma unroll
                for (int mb = 0; mb < 4; mb++) {
                    const bf16x8 av = *(const bf16x8*)(Vs + kb + (mb * 16 + r16) * 64 + (cpos0 ^ (s * 32)));
                    oB[mb] = __builtin_amdgcn_mfma_f32_16x16x32_bf16(av, bpB[s], oB[mb], 0, 0, 0);
                }
        }
    }

    // ---- epilogue: reduce l across the 4 lanes sharing each q, store ----
    lA += __shfl_xor(lA, 16); lA += __shfl_xor(lA, 32);
    lB += __shfl_xor(lB, 16); lB += __shfl_xor(lB, 32);
    {
        const float invA = 1.0f / lA;
        ushort_t* yp = y + ((size_t)(b * T_LEN + qA0 + qloc)) * C_DIM + h * HDIM;
#pragma unroll
        for (int mb = 0; mb < 4; mb++) {
            ushort4 o;
            o.x = f2bf(oA[mb][0] * invA);
            o.y = f2bf(oA[mb][1] * invA);
            o.z = f2bf(oA[mb][2] * invA);
            o.w = f2bf(oA[mb][3] * invA);
            *(ushort4*)(yp + mb * 16 + quad * 4) = o;
        }
    }
    {
        const float invB = 1.0f / lB;
        ushort_t* yp = y + ((size_t)(b * T_LEN + qB0 + qloc)) * C_DIM + h * HDIM;
#pragma unroll
        for (int mb = 0; mb < 4; mb++) {
            ushort4 o;
            o.x = f2bf(oB[mb][0] * invB);
            o.y = f2bf(oB[mb][1] * invB);
            o.z = f2bf(oB[mb][2] * invB);
            o.w = f2bf(oB[mb][3] * invB);
            *(ushort4*)(yp + mb * 16 + quad * 4) = o;
        }
    }
}

// ---------------------------------------------------------------------------
extern "C" void kernel_launch(void* const* d_in, const int* in_sizes, int n_in,
                              void* d_out, int out_size, void* d_ws, size_t ws_size,
                              hipStream_t stream)
{
    const float* x      = (const float*)d_in[0];
    const float* W_attn = (const float*)d_in[1];
    const float* b_attn = (const float*)d_in[2];
    const float* W_proj = (const float*)d_in[3];
    const float* b_proj = (const float*)d_in[4];
    float* out = (float*)d_out;

    const int M = 4 * T_LEN;  // 8192
    char* ws = (char*)d_ws;
    ushort_t* qkv = (ushort_t*)ws;
    ushort_t* xb  = (ushort_t*)(ws + 50331648);
    ushort_t* Wt1 = (ushort_t*)(ws + 67108864);
    ushort_t* yb  = (ushort_t*)(ws + 73400320);
    ushort_t* Wt2 = (ushort_t*)(ws + 90177536);
    ushort_t* vtg = (ushort_t*)(ws + 92274688);

    prep_inputs<<<9216, 256, 0, stream>>>(x, xb, W_attn, Wt1, W_proj, Wt2);

    // 1) qkv = x @ W_attn + b_attn  (bf16; Q slice pre-scaled by QK_SCALE)
    gemm_bt_mfma<true, true><<<dim3(C3 / 128, M / 128), 256, 0, stream>>>(
        xb, Wt1, b_attn, qkv, M, C3, C_DIM);

    transpose_v<<<dim3(T_LEN / 64, 4 * NHEAD), 256, 0, stream>>>(qkv, vtg);

    // 2) causal flash attention (paired q-tiles, XCD-swizzled) -> yb bf16
    attn_flash_mfma5<<<dim3(1024), 256, 0, stream>>>(qkv, vtg, yb);

    // 3) out = y @ W_proj + b_proj  (f32 out)
    gemm_bt_mfma<false, false><<<dim3(C_DIM / 128, M / 128), 256, 0, stream>>>(
        yb, Wt2, b_proj, out, M, C_DIM, C_DIM);
}